// Round 1
// baseline (8249.507 us; speedup 1.0000x reference)
//
#include <hip/hip_runtime.h>
#include <math.h>

#define R_TOTAL 8
#define CIN     256
#define COUT    256
#define HH      128
#define WW      128
#define BB      4

// ---------------------------------------------------------------------------
// Kernel A: bilinear-rotate the 3x3 filters, matching torch/jax affine_grid +
// grid_sample with align_corners=False and zero padding (all fp32).
// Writes rw laid out as [o][i][rcount][9] (rotation chunk-local).
// ---------------------------------------------------------------------------
__global__ void rotate_weights_kernel(const float* __restrict__ w,
                                      float* __restrict__ rw,
                                      int r0, int rcount) {
    int idx = blockIdx.x * blockDim.x + threadIdx.x;
    int total = COUT * CIN * rcount;
    if (idx >= total) return;
    int rr = idx % rcount;
    int ii = (idx / rcount) % CIN;
    int oo = idx / (rcount * CIN);
    int r  = r0 + rr;

    float ang = 6.283185307179586f * (float)r / 8.0f;
    float cs = cosf(ang), sn = sinf(ang);

    const float* wp = w  + ((size_t)oo * CIN + ii) * 9;
    float*       op = rw + (((size_t)oo * CIN + ii) * rcount + rr) * 9;

    #pragma unroll
    for (int ky = 0; ky < 3; ++ky) {
        #pragma unroll
        for (int kx = 0; kx < 3; ++kx) {
            // align_corners=False pixel-center coords in [-1,1]
            float yg = (2.0f * (float)ky + 1.0f) / 3.0f - 1.0f;
            float xg = (2.0f * (float)kx + 1.0f) / 3.0f - 1.0f;
            float xs = cs * xg - sn * yg;
            float ys = sn * xg + cs * yg;
            // unnormalize: ix = ((x+1)*W - 1)/2
            float ix = ((xs + 1.0f) * 3.0f - 1.0f) * 0.5f;
            float iy = ((ys + 1.0f) * 3.0f - 1.0f) * 0.5f;
            float ix0f = floorf(ix), iy0f = floorf(iy);
            float wx1 = ix - ix0f,  wy1 = iy - iy0f;
            float wx0 = 1.0f - wx1, wy0 = 1.0f - wy1;
            int ix0 = (int)ix0f, iy0 = (int)iy0f;
            int ix1 = ix0 + 1,   iy1 = iy0 + 1;

            float acc = 0.0f;
            if (iy0 >= 0 && iy0 < 3 && ix0 >= 0 && ix0 < 3)
                acc += wp[iy0 * 3 + ix0] * (wy0 * wx0);
            if (iy0 >= 0 && iy0 < 3 && ix1 >= 0 && ix1 < 3)
                acc += wp[iy0 * 3 + ix1] * (wy0 * wx1);
            if (iy1 >= 0 && iy1 < 3 && ix0 >= 0 && ix0 < 3)
                acc += wp[iy1 * 3 + ix0] * (wy1 * wx0);
            if (iy1 >= 0 && iy1 < 3 && ix1 >= 0 && ix1 < 3)
                acc += wp[iy1 * 3 + ix1] * (wy1 * wx1);
            op[ky * 3 + kx] = acc;
        }
    }
}

// ---------------------------------------------------------------------------
// Kernel B: direct conv (stride 1, pad 1) for RCOUNT rotations + max-reduce.
// Block = 256 threads (16x16), each thread computes a 2x2 pixel patch of a
// 32x32 output tile for one (b, o). Per input channel: stage 34x34 x-tile in
// LDS, 4x4 register window per thread, 8 rotation accumulators.
// rw layout: [o][i][RCOUNT][9]; weight reads are block-uniform -> scalar path.
// ---------------------------------------------------------------------------
template <int RCOUNT>
__global__ __launch_bounds__(256)
void rotconv_max_kernel(const float* __restrict__ x,
                        const float* __restrict__ rw,
                        float* __restrict__ out,
                        int first) {
    const int tid = threadIdx.x;
    const int tx = tid & 15;
    const int ty = tid >> 4;
    const int x0 = blockIdx.x * 32;
    const int y0 = blockIdx.y * 32;
    const int o  = blockIdx.z % COUT;
    const int b  = blockIdx.z / COUT;

    __shared__ float xs[34][36];   // +2 halo, pad cols to 36 for bank spread

    float acc[RCOUNT][2][2];
    #pragma unroll
    for (int r = 0; r < RCOUNT; ++r)
        #pragma unroll
        for (int py = 0; py < 2; ++py)
            #pragma unroll
            for (int px = 0; px < 2; ++px)
                acc[r][py][px] = 0.0f;

    for (int i = 0; i < CIN; ++i) {
        __syncthreads();
        const float* xp = x + ((size_t)(b * CIN + i)) * (HH * WW);
        for (int idx = tid; idx < 34 * 34; idx += 256) {
            int row = idx / 34, col = idx - row * 34;
            int gy = y0 - 1 + row, gx = x0 - 1 + col;
            float v = 0.0f;
            if (gy >= 0 && gy < HH && gx >= 0 && gx < WW)
                v = xp[gy * WW + gx];
            xs[row][col] = v;
        }
        __syncthreads();

        // 4x4 register window for this thread's 2x2 pixels
        float xv[4][4];
        #pragma unroll
        for (int ry = 0; ry < 4; ++ry)
            #pragma unroll
            for (int cx = 0; cx < 4; ++cx)
                xv[ry][cx] = xs[ty * 2 + ry][tx * 2 + cx];

        const float* wp = rw + ((size_t)(o * CIN + i)) * (RCOUNT * 9);
        #pragma unroll
        for (int r = 0; r < RCOUNT; ++r) {
            float wv[9];
            #pragma unroll
            for (int t = 0; t < 9; ++t) wv[t] = wp[r * 9 + t];
            #pragma unroll
            for (int py = 0; py < 2; ++py)
                #pragma unroll
                for (int px = 0; px < 2; ++px) {
                    float a = acc[r][py][px];
                    #pragma unroll
                    for (int ky = 0; ky < 3; ++ky)
                        #pragma unroll
                        for (int kx = 0; kx < 3; ++kx)
                            a += xv[py + ky][px + kx] * wv[ky * 3 + kx];
                    acc[r][py][px] = a;
                }
        }
    }

    #pragma unroll
    for (int py = 0; py < 2; ++py)
        #pragma unroll
        for (int px = 0; px < 2; ++px) {
            float m = acc[0][py][px];
            #pragma unroll
            for (int r = 1; r < RCOUNT; ++r) m = fmaxf(m, acc[r][py][px]);
            int oy = y0 + ty * 2 + py;
            int ox = x0 + tx * 2 + px;
            float* op = out + (((size_t)(b * COUT + o)) * HH + oy) * WW + ox;
            if (first) *op = m;
            else       *op = fmaxf(*op, m);
        }
}

// ---------------------------------------------------------------------------
extern "C" void kernel_launch(void* const* d_in, const int* in_sizes, int n_in,
                              void* d_out, int out_size, void* d_ws, size_t ws_size,
                              hipStream_t stream) {
    const float* x = (const float*)d_in[0];
    const float* w = (const float*)d_in[1];
    float* out = (float*)d_out;
    float* rw  = (float*)d_ws;

    // Pick the largest rotation chunk whose rotated-weight table fits in ws.
    int chunk = 8;
    while (chunk > 1 &&
           (size_t)COUT * CIN * chunk * 9 * sizeof(float) > ws_size)
        chunk >>= 1;

    int first = 1;
    for (int r0 = 0; r0 < R_TOTAL; r0 += chunk) {
        int rc = chunk;  // 8 is divisible by chunk
        int total = COUT * CIN * rc;
        rotate_weights_kernel<<<(total + 255) / 256, 256, 0, stream>>>(w, rw, r0, rc);

        dim3 grid(WW / 32, HH / 32, BB * COUT);
        switch (rc) {
            case 8: rotconv_max_kernel<8><<<grid, 256, 0, stream>>>(x, rw, out, first); break;
            case 4: rotconv_max_kernel<4><<<grid, 256, 0, stream>>>(x, rw, out, first); break;
            case 2: rotconv_max_kernel<2><<<grid, 256, 0, stream>>>(x, rw, out, first); break;
            default: rotconv_max_kernel<1><<<grid, 256, 0, stream>>>(x, rw, out, first); break;
        }
        first = 0;
    }
}

// Round 2
// 704.772 us; speedup vs baseline: 11.7052x; 11.7052x over previous
//
#include <hip/hip_runtime.h>
#include <hip/hip_bf16.h>
#include <math.h>

typedef __attribute__((ext_vector_type(8))) short bf16x8;
typedef __attribute__((ext_vector_type(4))) float f32x4;

#define R_TOTAL 8
#define CIN     256
#define COUT    256
#define HH      128
#define WW      128
#define BB      4
#define MTOT    (COUT * R_TOTAL)   // 2048
#define KTAPS   9

// ---------------------------------------------------------------------------
// async global->LDS, 16B per lane. LDS dest must be the wave-uniform base;
// HW writes lane l at base + l*16.
// ---------------------------------------------------------------------------
__device__ __forceinline__ void g2l16(void* lds, const void* g) {
    __builtin_amdgcn_global_load_lds(
        (const __attribute__((address_space(1))) unsigned int*)g,
        (__attribute__((address_space(3))) unsigned int*)lds,
        16, 0, 0);
}

// ---------------------------------------------------------------------------
// x (B,C,H,W) fp32 -> xb (B,H,W,C) bf16, LDS-tiled transpose.
// grid (HW/32, C/32, B), block 256.
// ---------------------------------------------------------------------------
__global__ __launch_bounds__(256)
void to_nhwc_bf16(const float* __restrict__ x, __hip_bfloat16* __restrict__ xb) {
    __shared__ __hip_bfloat16 t[32][33];
    const int b  = blockIdx.z;
    const int c0 = blockIdx.y * 32;
    const int p0 = blockIdx.x * 32;
    const int tx = threadIdx.x & 31;
    const int ty = threadIdx.x >> 5;           // 0..7
    const float* xp = x + (size_t)b * CIN * (HH * WW);
    #pragma unroll
    for (int j = 0; j < 4; ++j) {
        int c = ty * 4 + j;
        t[c][tx] = __float2bfloat16(xp[(size_t)(c0 + c) * (HH * WW) + p0 + tx]);
    }
    __syncthreads();
    __hip_bfloat16* op = xb + ((size_t)b * (HH * WW) + p0) * CIN + c0;
    #pragma unroll
    for (int j = 0; j < 4; ++j) {
        int p = ty * 4 + j;
        op[(size_t)p * CIN + tx] = t[tx][p];
    }
}

// ---------------------------------------------------------------------------
// Rotate weights (fp32 math, matches jax affine_grid/grid_sample,
// align_corners=False, zero pad) -> rwb[m][tap][i] bf16, m = o*8 + r.
// grid MTOT, block 256 (one m per block, i = threadIdx).
// ---------------------------------------------------------------------------
__global__ __launch_bounds__(256)
void rotate_weights_bf16(const float* __restrict__ w, __hip_bfloat16* __restrict__ rwb) {
    const int i = threadIdx.x;
    const int m = blockIdx.x;
    const int o = m >> 3, r = m & 7;

    float ang = 6.283185307179586f * (float)r / 8.0f;
    float cs = cosf(ang), sn = sinf(ang);

    const float* wp = w + ((size_t)o * CIN + i) * 9;
    __hip_bfloat16* op = rwb + (size_t)m * (KTAPS * CIN) + i;

    #pragma unroll
    for (int ky = 0; ky < 3; ++ky) {
        #pragma unroll
        for (int kx = 0; kx < 3; ++kx) {
            float yg = (2.0f * (float)ky + 1.0f) / 3.0f - 1.0f;
            float xg = (2.0f * (float)kx + 1.0f) / 3.0f - 1.0f;
            float xsf = cs * xg - sn * yg;
            float ysf = sn * xg + cs * yg;
            float ix = ((xsf + 1.0f) * 3.0f - 1.0f) * 0.5f;
            float iy = ((ysf + 1.0f) * 3.0f - 1.0f) * 0.5f;
            float ix0f = floorf(ix), iy0f = floorf(iy);
            float wx1 = ix - ix0f,  wy1 = iy - iy0f;
            float wx0 = 1.0f - wx1, wy0 = 1.0f - wy1;
            int ix0 = (int)ix0f, iy0 = (int)iy0f;
            int ix1 = ix0 + 1,   iy1 = iy0 + 1;
            float acc = 0.0f;
            if (iy0 >= 0 && iy0 < 3 && ix0 >= 0 && ix0 < 3) acc += wp[iy0*3+ix0] * (wy0*wx0);
            if (iy0 >= 0 && iy0 < 3 && ix1 >= 0 && ix1 < 3) acc += wp[iy0*3+ix1] * (wy0*wx1);
            if (iy1 >= 0 && iy1 < 3 && ix0 >= 0 && ix0 < 3) acc += wp[iy1*3+ix0] * (wy1*wx0);
            if (iy1 >= 0 && iy1 < 3 && ix1 >= 0 && ix1 < 3) acc += wp[iy1*3+ix1] * (wy1*wx1);
            op[(ky * 3 + kx) * CIN] = __float2bfloat16(acc);
        }
    }
}

// ---------------------------------------------------------------------------
// Main MFMA conv: block tile 128(M) x 128(N=one image row), 4 waves of 64x64,
// mfma_f32_16x16x32_bf16. K = 8 chunks(32ch) x 9 taps.
// LDS: xs[3 rows][130 cols][32 ch] (chunk window), As[2][128][32] (dbuf A).
// Channel-slot XOR swizzle (slot ^ ((col>>1)&3)) applied on the global SOURCE
// address at stage time and on the ds_read side (global_load_lds dest linear).
// ---------------------------------------------------------------------------
__global__ __launch_bounds__(256)
void rotconv_mfma_kernel(const __hip_bfloat16* __restrict__ xb,
                         const __hip_bfloat16* __restrict__ rwb,
                         float* __restrict__ out) {
    const int tid  = threadIdx.x;
    const int lane = tid & 63;
    const int w    = tid >> 6;
    const int wm   = w >> 1, wn = w & 1;
    const int q    = lane >> 4, lr = lane & 15;

    const int bid = blockIdx.x;
    const int mt  = bid >> 9;          // 0..15  (m-major -> XCD L2 reuse of A)
    const int nt  = bid & 511;
    const int b   = nt >> 7;
    const int y0  = nt & 127;
    const int m0  = mt << 7;

    __shared__ __align__(16) __hip_bfloat16 xs[3 * 130 * 32];
    __shared__ __align__(16) __hip_bfloat16 As[2][128 * 32];

    // zero xs once (covers border cols -1/128 and OOB rows; loads never touch them)
    {
        int* z = (int*)xs;
        for (int i2 = tid; i2 < (3 * 130 * 32) / 2; i2 += 256) z[i2] = 0;
    }

    // ---- per-thread precomputed read offsets (element units) ----
    int aOff[4];
    #pragma unroll
    for (int mi = 0; mi < 4; ++mi) {
        int row = wm * 64 + mi * 16 + lr;
        aOff[mi] = row * 32 + 8 * (q ^ ((row >> 1) & 3));
    }
    int bOff[4][3];
    #pragma unroll
    for (int ni = 0; ni < 4; ++ni)
        #pragma unroll
        for (int kx = 0; kx < 3; ++kx) {
            int colL = wn * 64 + ni * 16 + lr + kx;   // 0..129
            bOff[ni][kx] = colL * 32 + 8 * (q ^ ((colL >> 1) & 3));
        }

    // ---- staging bases ----
    // A: 2 wave-iterations cover 128 rows x 32 ch
    const __hip_bfloat16* srcA[2];
    int dstA[2];
    #pragma unroll
    for (int it = 0; it < 2; ++it) {
        int row = it * 64 + w * 16 + (lane >> 2);
        dstA[it] = (it * 64 + w * 16) * 32;                       // wave-uniform
        srcA[it] = rwb + (size_t)(m0 + row) * (KTAPS * CIN)
                       + 8 * ((lane & 3) ^ ((row >> 1) & 3));
    }
    // X: 6 wave-iterations cover 3 rows x 128 cols x 32 ch
    const __hip_bfloat16* srcX[6];
    int dstX[6];
    bool vX[6];
    #pragma unroll
    for (int it = 0; it < 6; ++it) {
        int wt = it * 4 + w;
        int rr = wt >> 3, cg = (wt & 7) * 16;
        int gy = y0 - 1 + rr;
        vX[it] = ((unsigned)gy < (unsigned)HH);
        int gx = cg + (lane >> 2);
        int colL = gx + 1;
        dstX[it] = (rr * 130 + 1 + cg) * 32;                      // wave-uniform
        srcX[it] = xb + ((size_t)((b * HH + gy) * WW + gx)) * CIN
                      + 8 * ((lane & 3) ^ ((colL >> 1) & 3));
    }

    f32x4 acc[4][4];
    #pragma unroll
    for (int mi = 0; mi < 4; ++mi)
        #pragma unroll
        for (int ni = 0; ni < 4; ++ni) {
            f32x4 z = {0.f, 0.f, 0.f, 0.f};
            acc[mi][ni] = z;
        }

    // prologue: stage A(tap0, chunk0) into buf 0
    #pragma unroll
    for (int it = 0; it < 2; ++it) g2l16(&As[0][dstA[it]], srcA[it]);
    __syncthreads();

    int buf = 0;
    for (int c = 0; c < 8; ++c) {
        const int i0 = c * 32;
        // stage x window for this chunk (previous chunk's reads done at last barrier)
        #pragma unroll
        for (int it = 0; it < 6; ++it)
            if (vX[it]) g2l16(&xs[dstX[it]], srcX[it] + i0);
        __syncthreads();

        #pragma unroll
        for (int t = 0; t < 9; ++t) {
            // prefetch next A tile into the other buffer
            if (t < 8) {
                #pragma unroll
                for (int it = 0; it < 2; ++it)
                    g2l16(&As[buf ^ 1][dstA[it]], srcA[it] + (t + 1) * CIN + i0);
            } else if (c < 7) {
                #pragma unroll
                for (int it = 0; it < 2; ++it)
                    g2l16(&As[buf ^ 1][dstA[it]], srcA[it] + i0 + 32);
            }

            bf16x8 af[4];
            #pragma unroll
            for (int mi = 0; mi < 4; ++mi)
                af[mi] = *(const bf16x8*)(&As[buf][aOff[mi]]);

            const int rr = t / 3, kx = t % 3;
            bf16x8 bfr[4];
            #pragma unroll
            for (int ni = 0; ni < 4; ++ni)
                bfr[ni] = *(const bf16x8*)(&xs[rr * (130 * 32) + bOff[ni][kx]]);

            #pragma unroll
            for (int mi = 0; mi < 4; ++mi)
                #pragma unroll
                for (int ni = 0; ni < 4; ++ni)
                    acc[mi][ni] = __builtin_amdgcn_mfma_f32_16x16x32_bf16(
                        af[mi], bfr[ni], acc[mi][ni], 0, 0, 0);

            buf ^= 1;
            __syncthreads();
        }
    }

    // epilogue: max over 8 rotations (4 regs + quarter-swap), write fp32
    const int oBase = (m0 + wm * 64) >> 3;
    #pragma unroll
    for (int mi = 0; mi < 4; ++mi) {
        #pragma unroll
        for (int ni = 0; ni < 4; ++ni) {
            f32x4 a4 = acc[mi][ni];
            float v = fmaxf(fmaxf(a4[0], a4[1]), fmaxf(a4[2], a4[3]));
            v = fmaxf(v, __shfl_xor(v, 16));
            if ((q & 1) == 0) {
                int o = oBase + mi * 2 + (q >> 1);
                int xcol = wn * 64 + ni * 16 + lr;
                out[(((size_t)(b * COUT + o)) * HH + y0) * WW + xcol] = v;
            }
        }
    }
}

// ===========================================================================
// Fallback fp32 path (round-0, known-correct) in case ws is too small.
// ===========================================================================
__global__ void rotate_weights_kernel(const float* __restrict__ w,
                                      float* __restrict__ rw,
                                      int r0, int rcount) {
    int idx = blockIdx.x * blockDim.x + threadIdx.x;
    int total = COUT * CIN * rcount;
    if (idx >= total) return;
    int rr = idx % rcount;
    int ii = (idx / rcount) % CIN;
    int oo = idx / (rcount * CIN);
    int r  = r0 + rr;
    float ang = 6.283185307179586f * (float)r / 8.0f;
    float cs = cosf(ang), sn = sinf(ang);
    const float* wp = w  + ((size_t)oo * CIN + ii) * 9;
    float*       op = rw + (((size_t)oo * CIN + ii) * rcount + rr) * 9;
    #pragma unroll
    for (int ky = 0; ky < 3; ++ky)
        #pragma unroll
        for (int kx = 0; kx < 3; ++kx) {
            float yg = (2.0f * ky + 1.0f) / 3.0f - 1.0f;
            float xg = (2.0f * kx + 1.0f) / 3.0f - 1.0f;
            float xsf = cs * xg - sn * yg;
            float ysf = sn * xg + cs * yg;
            float ix = ((xsf + 1.0f) * 3.0f - 1.0f) * 0.5f;
            float iy = ((ysf + 1.0f) * 3.0f - 1.0f) * 0.5f;
            float ix0f = floorf(ix), iy0f = floorf(iy);
            float wx1 = ix - ix0f,  wy1 = iy - iy0f;
            float wx0 = 1.0f - wx1, wy0 = 1.0f - wy1;
            int ix0 = (int)ix0f, iy0 = (int)iy0f;
            int ix1 = ix0 + 1,   iy1 = iy0 + 1;
            float acc = 0.0f;
            if (iy0 >= 0 && iy0 < 3 && ix0 >= 0 && ix0 < 3) acc += wp[iy0*3+ix0]*(wy0*wx0);
            if (iy0 >= 0 && iy0 < 3 && ix1 >= 0 && ix1 < 3) acc += wp[iy0*3+ix1]*(wy0*wx1);
            if (iy1 >= 0 && iy1 < 3 && ix0 >= 0 && ix0 < 3) acc += wp[iy1*3+ix0]*(wy1*wx0);
            if (iy1 >= 0 && iy1 < 3 && ix1 >= 0 && ix1 < 3) acc += wp[iy1*3+ix1]*(wy1*wx1);
            op[ky * 3 + kx] = acc;
        }
}

template <int RCOUNT>
__global__ __launch_bounds__(256)
void rotconv_max_kernel(const float* __restrict__ x,
                        const float* __restrict__ rw,
                        float* __restrict__ out,
                        int first) {
    const int tid = threadIdx.x;
    const int tx = tid & 15;
    const int ty = tid >> 4;
    const int x0 = blockIdx.x * 32;
    const int y0 = blockIdx.y * 32;
    const int o  = blockIdx.z % COUT;
    const int b  = blockIdx.z / COUT;
    __shared__ float xsm[34][36];
    float acc[RCOUNT][2][2];
    #pragma unroll
    for (int r = 0; r < RCOUNT; ++r)
        #pragma unroll
        for (int py = 0; py < 2; ++py)
            #pragma unroll
            for (int px = 0; px < 2; ++px) acc[r][py][px] = 0.0f;
    for (int i = 0; i < CIN; ++i) {
        __syncthreads();
        const float* xp = x + ((size_t)(b * CIN + i)) * (HH * WW);
        for (int idx = tid; idx < 34 * 34; idx += 256) {
            int row = idx / 34, col = idx - row * 34;
            int gy = y0 - 1 + row, gx = x0 - 1 + col;
            float v = 0.0f;
            if (gy >= 0 && gy < HH && gx >= 0 && gx < WW) v = xp[gy * WW + gx];
            xsm[row][col] = v;
        }
        __syncthreads();
        float xv[4][4];
        #pragma unroll
        for (int ry = 0; ry < 4; ++ry)
            #pragma unroll
            for (int cx = 0; cx < 4; ++cx) xv[ry][cx] = xsm[ty*2+ry][tx*2+cx];
        const float* wp = rw + ((size_t)(o * CIN + i)) * (RCOUNT * 9);
        #pragma unroll
        for (int r = 0; r < RCOUNT; ++r) {
            float wv[9];
            #pragma unroll
            for (int t2 = 0; t2 < 9; ++t2) wv[t2] = wp[r * 9 + t2];
            #pragma unroll
            for (int py = 0; py < 2; ++py)
                #pragma unroll
                for (int px = 0; px < 2; ++px) {
                    float a = acc[r][py][px];
                    #pragma unroll
                    for (int ky = 0; ky < 3; ++ky)
                        #pragma unroll
                        for (int kx = 0; kx < 3; ++kx)
                            a += xv[py+ky][px+kx] * wv[ky*3+kx];
                    acc[r][py][px] = a;
                }
        }
    }
    #pragma unroll
    for (int py = 0; py < 2; ++py)
        #pragma unroll
        for (int px = 0; px < 2; ++px) {
            float m = acc[0][py][px];
            #pragma unroll
            for (int r = 1; r < RCOUNT; ++r) m = fmaxf(m, acc[r][py][px]);
            int oy = y0 + ty * 2 + py;
            int ox = x0 + tx * 2 + px;
            float* op = out + (((size_t)(b * COUT + o)) * HH + oy) * WW + ox;
            if (first) *op = m;
            else       *op = fmaxf(*op, m);
        }
}

// ===========================================================================
extern "C" void kernel_launch(void* const* d_in, const int* in_sizes, int n_in,
                              void* d_out, int out_size, void* d_ws, size_t ws_size,
                              hipStream_t stream) {
    const float* x = (const float*)d_in[0];
    const float* w = (const float*)d_in[1];
    float* out = (float*)d_out;

    const size_t xbBytes = (size_t)BB * HH * WW * CIN * sizeof(__hip_bfloat16); // 33.5 MB
    const size_t rwBytes = (size_t)MTOT * KTAPS * CIN * sizeof(__hip_bfloat16); // 9.4 MB

    if (ws_size >= xbBytes + rwBytes) {
        __hip_bfloat16* xbuf = (__hip_bfloat16*)d_ws;
        __hip_bfloat16* rwb  = (__hip_bfloat16*)((char*)d_ws + xbBytes);

        to_nhwc_bf16<<<dim3((HH * WW) / 32, CIN / 32, BB), 256, 0, stream>>>(x, xbuf);
        rotate_weights_bf16<<<MTOT, 256, 0, stream>>>(w, rwb);
        rotconv_mfma_kernel<<<16 * 512, 256, 0, stream>>>(xbuf, rwb, out);
        return;
    }

    // ---- fallback fp32 path ----
    float* rw = (float*)d_ws;
    int chunk = 8;
    while (chunk > 1 && (size_t)COUT * CIN * chunk * 9 * sizeof(float) > ws_size)
        chunk >>= 1;
    int first = 1;
    for (int r0 = 0; r0 < R_TOTAL; r0 += chunk) {
        int rc = chunk;
        int total = COUT * CIN * rc;
        rotate_weights_kernel<<<(total + 255) / 256, 256, 0, stream>>>(w, rw, r0, rc);
        dim3 grid(WW / 32, HH / 32, BB * COUT);
        switch (rc) {
            case 8: rotconv_max_kernel<8><<<grid, 256, 0, stream>>>(x, rw, out, first); break;
            case 4: rotconv_max_kernel<4><<<grid, 256, 0, stream>>>(x, rw, out, first); break;
            case 2: rotconv_max_kernel<2><<<grid, 256, 0, stream>>>(x, rw, out, first); break;
            default: rotconv_max_kernel<1><<<grid, 256, 0, stream>>>(x, rw, out, first); break;
        }
        first = 0;
    }
}